// Round 15
// baseline (232.580 us; speedup 1.0000x reference)
//
#include <hip/hip_runtime.h>

#define T_LEN 4096
#define H 16
#define N 16
#define D 64
#define NC 256
#define CL (T_LEN / NC)   // 16
#define NG 16             // chunk groups of 16 chunks
#define HND (H * N * D)   // 16384

static __device__ __forceinline__ unsigned short f2bf(float f) {
    union { float f; unsigned u; } v; v.f = f;
    unsigned r = (v.u + 0x7fffu + ((v.u >> 16) & 1u)) >> 16;
    return (unsigned short)r;
}
static __device__ __forceinline__ float bf2f(unsigned short s) {
    union { unsigned u; float f; } v; v.u = ((unsigned)s) << 16;
    return v.f;
}

// ---------------------------------------------------------------------------
// K1 (= r14 k1_local, proven): one wave per (chunk c, head h), 4096 waves.
// Local scan from zero WITH fused C-projection. Writes L[c][h][n][d] (bf16),
// P[h][c] (f32), out_local (f32, ws).
// ---------------------------------------------------------------------------
__global__ __launch_bounds__(64)
void k1_local(const float* __restrict__ x, const float* __restrict__ dt,
              const float* __restrict__ B, const float* __restrict__ C,
              const float* __restrict__ mask, const float* __restrict__ log_decay,
              const float* __restrict__ skip_weight,
              unsigned short* __restrict__ Lb, float* __restrict__ Pbuf,
              float* __restrict__ OL) {
    const int c = blockIdx.x, h = blockIdx.y;
    const int d = threadIdx.x;
    const float rate = -__expf(log_decay[h]);
    const int t0 = c * CL;

    __shared__ float Bs[CL * N], Cs[CL * N];     // 2 KB, B dt-scaled
    {
        const float4* Bg = (const float4*)B;
        const float4* Cg = (const float4*)C;
        const int j = d;                         // CL*N/4 = 64 -> 1 per lane
        const int row = j >> 2, off = j & 3;
        const float dtv = dt[(t0 + row) * H + h];
        float4 bv = Bg[((t0 + row) * H + h) * (N / 4) + off];
        bv.x *= dtv; bv.y *= dtv; bv.z *= dtv; bv.w *= dtv;
        ((float4*)Bs)[j] = bv;
        ((float4*)Cs)[j] = Cg[((t0 + row) * H + h) * (N / 4) + off];
    }
    __syncthreads();

    float s[N];
#pragma unroll
    for (int n = 0; n < N; ++n) s[n] = 0.f;
    const float swv = skip_weight[h * D + d];
    float P = 1.f;

#pragma unroll
    for (int ss = 0; ss < CL; ++ss) {
        const int t = t0 + ss;
        const float dtv = dt[t * H + h];          // s_load
        const float mv  = mask[t];                // s_load
        const float a   = (1.f - mv) * __expf(dtv * rate);
        const float xv  = x[(t * H + h) * D + d]; // per-lane coalesced
        P *= a;
        float acc = swv * xv;
        const float4* Br4 = (const float4*)(Bs + ss * N);
        const float4* Cr4 = (const float4*)(Cs + ss * N);
#pragma unroll
        for (int q = 0; q < 4; ++q) {             // ds_read_b128 broadcast
            const float4 bv = Br4[q];
            const float4 cv = Cr4[q];
            s[4*q+0] = a * s[4*q+0] + bv.x * xv;  acc += cv.x * s[4*q+0];
            s[4*q+1] = a * s[4*q+1] + bv.y * xv;  acc += cv.y * s[4*q+1];
            s[4*q+2] = a * s[4*q+2] + bv.z * xv;  acc += cv.z * s[4*q+2];
            s[4*q+3] = a * s[4*q+3] + bv.w * xv;  acc += cv.w * s[4*q+3];
        }
        OL[(t * H + h) * D + d] = acc;            // out_local
    }

    unsigned short* Lp = Lb + ((size_t)(c * H + h) * N) * D + d;
#pragma unroll
    for (int n = 0; n < N; ++n) Lp[n * D] = f2bf(s[n]);
    if (d == 0) Pbuf[h * NC + c] = P;             // [h][c]
}

// ---------------------------------------------------------------------------
// K2: fused combine + correction (flag protocol proven correct in r12; the
// register-pressure failure mode is gone because the local-scan state now
// lives in K1/OL -- both roles here are lean, <~100 VGPR, no spills).
//  Blocks 0..255 (combine): serial sweep over 256 chunks (8 rounds x
//    32-deep prefetch), overwrites Lb with ENTRY states, publishes
//    Eflag[h][group] per 16-chunk group, writes next_carry.
//  Blocks 256..2303 (correction, 2 chunks each): stage C panel, issue OL
//    reads (overlap the wait), spin on group flag, then
//    out[t] = OL[t] + pa(t) * (C_t . E)    (linearity).
//  All 2304 single-wave blocks co-resident at 4 waves/SIMD -> no starvation;
//  only correction waits on combine, never the reverse.
// ---------------------------------------------------------------------------
__global__ __launch_bounds__(64)
void k2_fused(const float* __restrict__ dt, const float* __restrict__ C,
              const float* __restrict__ mask, const float* __restrict__ log_decay,
              const float* __restrict__ ic,
              unsigned short* __restrict__ Lb, const float* __restrict__ Pbuf,
              const float* __restrict__ OL, unsigned* __restrict__ Eflag,
              float* __restrict__ out) {
    const int d = threadIdx.x;
    const int bi = blockIdx.x;

    if (bi < 256) {
        // ---------------- combine role ----------------
        const int idx = bi * 64 + d;              // h*1024 + n*64 + d
        const int h = bi >> 4;                    // wave-uniform
        float carry = ic[idx];
#pragma unroll 1
        for (int r = 0; r < NC / 32; ++r) {       // 8 rounds, 32-deep prefetch
            float l[32];
#pragma unroll
            for (int k = 0; k < 32; ++k)
                l[k] = bf2f(Lb[(size_t)(r * 32 + k) * HND + idx]);
#pragma unroll
            for (int k = 0; k < 32; ++k) {
                const int kk = r * 32 + k;
                const float p = Pbuf[h * NC + kk];        // s_load
                Lb[(size_t)kk * HND + idx] = f2bf(carry); // entry state
                carry = p * carry + l[k];
                if ((kk & 15) == 15) {
                    __threadfence();                      // release entries
                    if (d == 0) atomicAdd(&Eflag[h * NG + (kk >> 4)], 1u);
                }
            }
        }
        out[idx] = carry;                          // next_carry
    } else {
        // ---------------- correction role (2 chunks, same flag group) -----
        const int g = bi - 256;                    // 0..2047
        const int h = g & 15, cA = (g >> 4) * 2;   // chunks cA, cA+1
        const float rate = -__expf(log_decay[h]);
        const int t00 = cA * CL;

        __shared__ float Cs[2 * CL * N];           // 2 KB
        {
            const float4* Cg = (const float4*)C;
#pragma unroll
            for (int i = 0; i < 2; ++i) {
                const int j = i * 64 + d;
                const int row = j >> 2, off = j & 3;   // rows 0..31 (2 chunks)
                ((float4*)Cs)[j] = Cg[((t00 + row) * H + h) * (N / 4) + off];
            }
        }

        // issue OL reads for both chunks BEFORE the wait (latency overlap)
        float ol[2 * CL];
#pragma unroll
        for (int ss = 0; ss < 2 * CL; ++ss)
            ol[ss] = OL[((t00 + ss) * H + h) * D + d];
        __syncthreads();

        // wait for entry states of our group (cA, cA+1 share group cA>>4)
        const unsigned* flag = &Eflag[h * NG + (cA >> 4)];
        while (__hip_atomic_load(flag, __ATOMIC_RELAXED, __HIP_MEMORY_SCOPE_AGENT) < 16u)
            __builtin_amdgcn_s_sleep(2);
        __threadfence();                           // acquire

        float* outp = out + HND;
#pragma unroll
        for (int half = 0; half < 2; ++half) {
            const int c = cA + half;
            const unsigned short* Ep = Lb + ((size_t)(c * H + h) * N) * D + d;
            float E[N];
#pragma unroll
            for (int n = 0; n < N; ++n) E[n] = bf2f(Ep[n * D]);
            float pa = 1.f;
            const int t0 = c * CL;
#pragma unroll
            for (int ss = 0; ss < CL; ++ss) {
                const int t = t0 + ss;
                const float dtv = dt[t * H + h];   // L2-resident s_load
                const float mv  = mask[t];
                pa *= (1.f - mv) * __expf(dtv * rate);
                const float4* Cr4 = (const float4*)(Cs + (half * CL + ss) * N);
                float corr = 0.f;
#pragma unroll
                for (int q = 0; q < 4; ++q) {
                    const float4 cv = Cr4[q];
                    corr += cv.x * E[4*q+0] + cv.y * E[4*q+1]
                          + cv.z * E[4*q+2] + cv.w * E[4*q+3];
                }
                __builtin_nontemporal_store(ol[half * CL + ss] + pa * corr,
                                            &outp[(t * H + h) * D + d]);
            }
        }
    }
}

extern "C" void kernel_launch(void* const* d_in, const int* in_sizes, int n_in,
                              void* d_out, int out_size, void* d_ws, size_t ws_size,
                              hipStream_t stream) {
    const float* x    = (const float*)d_in[0];
    const float* dt   = (const float*)d_in[1];
    const float* B    = (const float*)d_in[2];
    const float* C    = (const float*)d_in[3];
    const float* mask = (const float*)d_in[4];
    const float* ic   = (const float*)d_in[5];
    const float* ld   = (const float*)d_in[6];
    const float* sw   = (const float*)d_in[7];
    float* out = (float*)d_out;

    // ws: [Eflag 1KB][Pbuf 16KB @ +4KB][Lb bf16 8.4MB @ +32KB][OL f32 after]
    unsigned* Eflag = (unsigned*)d_ws;
    float* Pbuf = (float*)((char*)d_ws + 4096);
    unsigned short* Lb = (unsigned short*)((char*)d_ws + 32768);
    float* OL = (float*)((char*)d_ws + 32768 + (size_t)NC * HND * 2);

    hipMemsetAsync(Eflag, 0, H * NG * sizeof(unsigned), stream);

    k1_local<<<dim3(NC, H), dim3(64), 0, stream>>>(x, dt, B, C, mask, ld, sw,
                                                   Lb, Pbuf, OL);
    k2_fused<<<dim3(256 + NC * H / 2), dim3(64), 0, stream>>>(
        dt, C, mask, ld, ic, Lb, Pbuf, OL, Eflag, out);
}

// Round 16
// 35.495 us; speedup vs baseline: 6.5526x; 6.5526x over previous
//
#include <hip/hip_runtime.h>

#define T_LEN 4096
#define H 16
#define N 16
#define D 64
#define NC 256
#define CL (T_LEN / NC)   // 16
#define CPB 4             // chunks (waves) per block
#define HND (H * N * D)   // 16384

static __device__ __forceinline__ unsigned short f2bf(float f) {
    union { float f; unsigned u; } v; v.f = f;
    unsigned r = (v.u + 0x7fffu + ((v.u >> 16) & 1u)) >> 16;
    return (unsigned short)r;
}
static __device__ __forceinline__ float bf2f(unsigned short s) {
    union { unsigned u; float f; } v; v.u = ((unsigned)s) << 16;
    return v.f;
}

// ---------------------------------------------------------------------------
// K1: 4-wave blocks, one head x 4 consecutive chunks. Wave w scans chunk
// cq*4+w from zero. Contiguous 16KB B-panel staging per block (dt-scaled);
// A-table (decay factors) computed once here, stored [h][T] for K3.
// Writes L[c][h][n][d] (bf16), P[h][c] (f32), A (f32).
// ---------------------------------------------------------------------------
__global__ __launch_bounds__(256)
void k1_local(const float* __restrict__ x, const float* __restrict__ dt,
              const float* __restrict__ B, const float* __restrict__ mask,
              const float* __restrict__ log_decay,
              unsigned short* __restrict__ Lb, float* __restrict__ Pbuf,
              float* __restrict__ Abuf) {
    const int cq = blockIdx.x, h = blockIdx.y;
    const int tid = threadIdx.x;
    const int w = tid >> 6, d = tid & 63;
    const int c = cq * CPB + w;
    const int t00 = cq * CPB * CL;                 // 64 t-rows per block
    const float rate = -__expf(log_decay[h]);

    __shared__ float Bs[CPB * CL * N];             // 4 KB, dt-scaled
    __shared__ float As[CPB * CL];                 // 256 B
    {
        const float4* Bg = (const float4*)B;
        const int j = tid;                         // exactly 256 float4s
        const int row = j >> 2, off = j & 3;
        const int t = t00 + row;
        const float dtv = dt[t * H + h];
        float4 bv = Bg[(t * H + h) * (N / 4) + off];
        bv.x *= dtv; bv.y *= dtv; bv.z *= dtv; bv.w *= dtv;
        ((float4*)Bs)[j] = bv;
        if (off == 0) {
            const float av = (1.f - mask[t]) * __expf(dtv * rate);
            As[row] = av;
            Abuf[h * T_LEN + t] = av;              // [h][T]: coalesced in K3
        }
    }
    __syncthreads();

    float s[N];
#pragma unroll
    for (int n = 0; n < N; ++n) s[n] = 0.f;
    float P = 1.f;
    const int t0 = c * CL;

#pragma unroll
    for (int ss = 0; ss < CL; ++ss) {
        const float a  = As[w * CL + ss];          // LDS broadcast
        const float xv = x[((t0 + ss) * H + h) * D + d];
        P *= a;
        const float4* Br4 = (const float4*)(Bs + (w * CL + ss) * N);
#pragma unroll
        for (int q = 0; q < 4; ++q) {              // ds_read_b128 broadcast
            const float4 bv = Br4[q];
            s[4*q+0] = a * s[4*q+0] + bv.x * xv;
            s[4*q+1] = a * s[4*q+1] + bv.y * xv;
            s[4*q+2] = a * s[4*q+2] + bv.z * xv;
            s[4*q+3] = a * s[4*q+3] + bv.w * xv;
        }
    }

    unsigned short* Lp = Lb + ((size_t)(c * H + h) * N) * D + d;
#pragma unroll
    for (int n = 0; n < N; ++n) Lp[n * D] = f2bf(s[n]);
    if (d == 0) Pbuf[h * NC + c] = P;              // [h][c]
}

// ---------------------------------------------------------------------------
// K2 (proven r14): 16384 threads, one per (h,n,d). 2 rounds of 128-deep
// prefetch; h block-uniform -> P reads are s_loads. Overwrites L in place
// with chunk ENTRY states (bf16); writes next_carry (f32).
// ---------------------------------------------------------------------------
__global__ __launch_bounds__(256)
void k2_combine(const float* __restrict__ initial_carry,
                unsigned short* __restrict__ LE, const float* __restrict__ Pbuf,
                float* __restrict__ next_carry) {
    const int idx = blockIdx.x * 256 + threadIdx.x;  // h*1024 + n*64 + d
    const int h = blockIdx.x >> 2;                   // block-uniform
    float carry = initial_carry[idx];

#pragma unroll 1
    for (int r = 0; r < NC / 128; ++r) {             // 2 rounds
        float l[128];
#pragma unroll
        for (int k = 0; k < 128; ++k)
            l[k] = bf2f(LE[(size_t)(r * 128 + k) * HND + idx]);
#pragma unroll
        for (int k = 0; k < 128; ++k) {
            const float p = Pbuf[h * NC + r * 128 + k];          // s_load
            LE[(size_t)(r * 128 + k) * HND + idx] = f2bf(carry); // entry
            carry = p * carry + l[k];
        }
    }
    next_carry[idx] = carry;
}

// ---------------------------------------------------------------------------
// K3: 4-wave blocks mirroring K1. Wave w re-scans chunk cq*4+w from its
// bf16 entry state with fused C-projection + skip. A from table (no exp,
// no mask). Nontemporal output stores.
// ---------------------------------------------------------------------------
__global__ __launch_bounds__(256)
void k3_scan(const float* __restrict__ x, const float* __restrict__ dt,
             const float* __restrict__ B, const float* __restrict__ C,
             const float* __restrict__ skip_weight,
             const float* __restrict__ Abuf,
             const unsigned short* __restrict__ Eb, float* __restrict__ out) {
    const int cq = blockIdx.x, h = blockIdx.y;
    const int tid = threadIdx.x;
    const int w = tid >> 6, d = tid & 63;
    const int c = cq * CPB + w;
    const int t00 = cq * CPB * CL;

    __shared__ float Bs[CPB * CL * N], Cs[CPB * CL * N];  // 8 KB
    __shared__ float As[CPB * CL];
    {
        const float4* Bg = (const float4*)B;
        const float4* Cg = (const float4*)C;
        const int j = tid;
        const int row = j >> 2, off = j & 3;
        const int t = t00 + row;
        const float dtv = dt[t * H + h];
        float4 bv = Bg[(t * H + h) * (N / 4) + off];
        bv.x *= dtv; bv.y *= dtv; bv.z *= dtv; bv.w *= dtv;
        ((float4*)Bs)[j] = bv;
        ((float4*)Cs)[j] = Cg[(t * H + h) * (N / 4) + off];
        if (tid < CPB * CL) As[tid] = Abuf[h * T_LEN + t00 + tid]; // coalesced
    }
    __syncthreads();

    float s[N];
    const unsigned short* Ep = Eb + ((size_t)(c * H + h) * N) * D + d;
#pragma unroll
    for (int n = 0; n < N; ++n) s[n] = bf2f(Ep[n * D]);

    const float swv = skip_weight[h * D + d];
    const int t0 = c * CL;
#pragma unroll
    for (int ss = 0; ss < CL; ++ss) {
        const int t = t0 + ss;
        const float a  = As[w * CL + ss];
        const float xv = x[(t * H + h) * D + d];
        float acc = swv * xv;
        const float4* Br4 = (const float4*)(Bs + (w * CL + ss) * N);
        const float4* Cr4 = (const float4*)(Cs + (w * CL + ss) * N);
#pragma unroll
        for (int q = 0; q < 4; ++q) {
            const float4 bv = Br4[q];
            const float4 cv = Cr4[q];
            s[4*q+0] = a * s[4*q+0] + bv.x * xv;  acc += cv.x * s[4*q+0];
            s[4*q+1] = a * s[4*q+1] + bv.y * xv;  acc += cv.y * s[4*q+1];
            s[4*q+2] = a * s[4*q+2] + bv.z * xv;  acc += cv.z * s[4*q+2];
            s[4*q+3] = a * s[4*q+3] + bv.w * xv;  acc += cv.w * s[4*q+3];
        }
        __builtin_nontemporal_store(acc, &out[(t * H + h) * D + d]);
    }
}

extern "C" void kernel_launch(void* const* d_in, const int* in_sizes, int n_in,
                              void* d_out, int out_size, void* d_ws, size_t ws_size,
                              hipStream_t stream) {
    const float* x    = (const float*)d_in[0];
    const float* dt   = (const float*)d_in[1];
    const float* B    = (const float*)d_in[2];
    const float* C    = (const float*)d_in[3];
    const float* mask = (const float*)d_in[4];
    const float* ic   = (const float*)d_in[5];
    const float* ld   = (const float*)d_in[6];
    const float* sw   = (const float*)d_in[7];
    float* out = (float*)d_out;

    // ws: [Pbuf 16KB][Abuf 256KB @ +16KB][Lb bf16 8.4MB @ +272KB]
    float* Pbuf = (float*)d_ws;
    float* Abuf = (float*)((char*)d_ws + 16384);
    unsigned short* Lb = (unsigned short*)((char*)d_ws + 16384 + T_LEN * H * 4);

    dim3 grid(NC / CPB, H), block(256);
    k1_local<<<grid, block, 0, stream>>>(x, dt, B, mask, ld, Lb, Pbuf, Abuf);
    k2_combine<<<dim3(HND / 256), dim3(256), 0, stream>>>(ic, Lb, Pbuf, out);
    k3_scan<<<grid, block, 0, stream>>>(x, dt, B, C, sw, Abuf, Lb, out + HND);
}